// Round 2
// baseline (4445.464 us; speedup 1.0000x reference)
//
#include <hip/hip_runtime.h>

#define NODES_CH 128   // IN_CH == HID == 128
#define OUTW 64

// ---------------- CSR build ----------------

__global__ void k_zero(int* __restrict__ p, int n) {
    int i = blockIdx.x * blockDim.x + threadIdx.x;
    if (i < n) p[i] = 0;
}

__global__ void k_degree(const int* __restrict__ dstI, int* __restrict__ deg, int E) {
    int e = blockIdx.x * blockDim.x + threadIdx.x;
    if (e < E) atomicAdd(&deg[dstI[e]], 1);
}

// single-block exclusive scan; also inits cursor
__global__ __launch_bounds__(1024)
void k_scan(const int* __restrict__ deg, int* __restrict__ rp,
            int* __restrict__ cursor, int n) {
    __shared__ int wsum[16];
    int tid  = threadIdx.x;
    int lane = tid & 63;
    int wid  = tid >> 6;
    int carry = 0;
    for (int base = 0; base < n; base += 1024) {
        int i = base + tid;
        int v = (i < n) ? deg[i] : 0;
        int x = v;
        #pragma unroll
        for (int off = 1; off < 64; off <<= 1) {
            int t = __shfl_up(x, off, 64);
            if (lane >= off) x += t;
        }
        if (lane == 63) wsum[wid] = x;
        __syncthreads();
        if (wid == 0) {
            int y = (lane < 16) ? wsum[lane] : 0;
            #pragma unroll
            for (int off = 1; off < 16; off <<= 1) {
                int t = __shfl_up(y, off, 64);
                if (lane >= off) y += t;
            }
            if (lane < 16) wsum[lane] = y;
        }
        __syncthreads();
        int woff  = (wid > 0) ? wsum[wid - 1] : 0;
        int incl  = x + woff;
        int total = wsum[15];
        if (i < n) {
            int ex = carry + incl - v;
            rp[i] = ex;
            cursor[i] = ex;
        }
        carry += total;
        __syncthreads();  // protect wsum before next chunk overwrites
    }
    if (tid == 0) rp[n] = carry;
}

__global__ void k_fill(const int* __restrict__ srcI, const int* __restrict__ dstI,
                       int* __restrict__ cursor, int* __restrict__ colA, int E) {
    int e = blockIdx.x * blockDim.x + threadIdx.x;
    if (e < E) {
        int d = dstI[e];
        int p = atomicAdd(&cursor[d], 1);
        colA[p] = srcI[e];
    }
}

// ---------------- mean aggregation (gather over CSR) ----------------
// one WAVE per node; 32 lanes x float4 = one 512B row; lane halves take
// alternate edges (2 rows in flight per load instr), x2 manual unroll.
__global__ __launch_bounds__(256)
void k_agg(const float* __restrict__ X, const int* __restrict__ rp,
           const int* __restrict__ colA, float* __restrict__ out, int n) {
    int node = (blockIdx.x << 2) + (threadIdx.x >> 6);
    if (node >= n) return;
    int lane = threadIdx.x & 63;
    int eh = lane >> 5;   // which edge parity this half-wave takes
    int c4 = lane & 31;   // float4 slot within the 128-float row
    int beg = rp[node], end = rp[node + 1];
    const float4* __restrict__ X4 = (const float4*)X;
    float4 s = make_float4(0.f, 0.f, 0.f, 0.f);
    int e = beg + eh;
    // 2 edges per half-wave in flight
    for (; e + 2 < end; e += 4) {
        int c0 = colA[e];
        int c1 = colA[e + 2];
        float4 v0 = X4[(size_t)c0 * 32 + c4];
        float4 v1 = X4[(size_t)c1 * 32 + c4];
        s.x += v0.x + v1.x; s.y += v0.y + v1.y;
        s.z += v0.z + v1.z; s.w += v0.w + v1.w;
    }
    if (e < end) {
        int c0 = colA[e];
        float4 v0 = X4[(size_t)c0 * 32 + c4];
        s.x += v0.x; s.y += v0.y; s.z += v0.z; s.w += v0.w;
    }
    s.x += __shfl_xor(s.x, 32);
    s.y += __shfl_xor(s.y, 32);
    s.z += __shfl_xor(s.z, 32);
    s.w += __shfl_xor(s.w, 32);
    if (eh == 0) {
        float inv = 1.f / (float)((end > beg) ? (end - beg) : 1);
        ((float4*)out)[(size_t)node * 32 + c4] =
            make_float4(s.x * inv, s.y * inv, s.z * inv, s.w * inv);
    }
}

// ---------------- fused SAGE linear ----------------
// out(cols of this y-block) = A0 @ W0 + A1 @ W1 + bias, optional relu.
// Grid: (ceil(N/64), 2). Block 256 thr: cg=tid>>4 (16 col groups x 4 cols),
// rg=tid&15 (16 row groups x 4 rows) -> 64x64 tile, 4x4 acc/thread.
// W staged per 64-K chunk: 16 KiB LDS. W-read addr = cg*16B -> conflict-free.
template <int RELU>
__global__ __launch_bounds__(256, 4)
void k_gemm(const float* __restrict__ A0, const float* __restrict__ A1,
            const float* __restrict__ W0a, const float* __restrict__ W0b,
            const float* __restrict__ W1a, const float* __restrict__ W1b,
            const float* __restrict__ ba, const float* __restrict__ bb,
            float* __restrict__ o0, float* __restrict__ o1,
            int wstride, int ostride, int N) {
    __shared__ float Wlds[64 * 64];  // 16 KiB
    const int tid = threadIdx.x;
    const int cg = tid >> 4;
    const int rg = tid & 15;
    const int cb = blockIdx.y;
    const int rbase = blockIdx.x * 64 + rg * 4;

    float acc[4][4];
    #pragma unroll
    for (int r = 0; r < 4; r++)
        #pragma unroll
        for (int c = 0; c < 4; c++) acc[r][c] = 0.f;

    #pragma unroll
    for (int phase = 0; phase < 2; ++phase) {
        const float* __restrict__ A = phase ? A1 : A0;
        const float* __restrict__ W = phase ? (cb ? W1b : W1a) : (cb ? W0b : W0a);
        for (int kc = 0; kc < 2; ++kc) {
            __syncthreads();
            // stage W rows [kc*64, kc*64+64), 64 cols -> Wlds[64][64]
            #pragma unroll
            for (int i = tid; i < 64 * 16; i += 256) {
                int kr = i >> 4, c4 = i & 15;
                ((float4*)Wlds)[i] =
                    *(const float4*)(W + (size_t)(kc * 64 + kr) * wstride + c4 * 4);
            }
            __syncthreads();
            for (int k = 0; k < 64; k += 4) {
                float4 a[4];
                #pragma unroll
                for (int r = 0; r < 4; r++) {
                    int row = rbase + r;
                    a[r] = (row < N)
                        ? *(const float4*)(A + (size_t)row * 128 + kc * 64 + k)
                        : make_float4(0.f, 0.f, 0.f, 0.f);
                }
                #pragma unroll
                for (int kk = 0; kk < 4; kk++) {
                    float4 w = *(const float4*)(Wlds + (k + kk) * 64 + cg * 4);
                    #pragma unroll
                    for (int r = 0; r < 4; r++) {
                        float av = (kk == 0) ? a[r].x : (kk == 1) ? a[r].y
                                 : (kk == 2) ? a[r].z : a[r].w;
                        acc[r][0] += av * w.x;
                        acc[r][1] += av * w.y;
                        acc[r][2] += av * w.z;
                        acc[r][3] += av * w.w;
                    }
                }
            }
        }
    }

    const float4 bv = *(const float4*)((cb ? bb : ba) + cg * 4);
    float* __restrict__ obase = cb ? o1 : o0;
    #pragma unroll
    for (int r = 0; r < 4; r++) {
        int row = rbase + r;
        if (row >= N) continue;
        float4 v;
        v.x = acc[r][0] + bv.x;
        v.y = acc[r][1] + bv.y;
        v.z = acc[r][2] + bv.z;
        v.w = acc[r][3] + bv.w;
        if (RELU) {
            v.x = fmaxf(v.x, 0.f); v.y = fmaxf(v.y, 0.f);
            v.z = fmaxf(v.z, 0.f); v.w = fmaxf(v.w, 0.f);
        }
        *(float4*)(obase + (size_t)row * ostride + cg * 4) = v;
    }
}

// ---------------- launch ----------------

extern "C" void kernel_launch(void* const* d_in, const int* in_sizes, int n_in,
                              void* d_out, int out_size, void* d_ws, size_t ws_size,
                              hipStream_t stream) {
    const float* x     = (const float*)d_in[0];
    const int*   ei    = (const int*)d_in[1];
    const float* W1_l  = (const float*)d_in[2];
    const float* b1    = (const float*)d_in[3];
    const float* W1_r  = (const float*)d_in[4];
    const float* Wmu_l = (const float*)d_in[5];
    const float* bmu   = (const float*)d_in[6];
    const float* Wmu_r = (const float*)d_in[7];
    const float* Wls_l = (const float*)d_in[8];
    const float* bls   = (const float*)d_in[9];
    const float* Wls_r = (const float*)d_in[10];

    const int N = in_sizes[0] / NODES_CH;  // 50000
    const int E = in_sizes[1] / 2;         // 800000
    const int* srcI = ei;
    const int* dstI = ei + E;

    const int NP = (N + 63) & ~63;
    const int EP = (E + 15) & ~15;

    char* w = (char*)d_ws;
    int* deg    = (int*)w;  w += (size_t)NP * 4;
    int* rp     = (int*)w;  w += (size_t)(NP + 64) * 4;
    int* cursor = (int*)w;  w += (size_t)NP * 4;
    int* colA   = (int*)w;  w += (size_t)EP * 4;
    float* meanb = (float*)w;  w += (size_t)N * 128 * 4;
    float* h     = (float*)w;  w += (size_t)N * 128 * 4;

    float* out_mu = (float*)d_out;
    float* out_ls = out_mu + (size_t)N * OUTW;

    // CSR build
    k_zero<<<(N + 255) / 256, 256, 0, stream>>>(deg, N);
    k_degree<<<(E + 255) / 256, 256, 0, stream>>>(dstI, deg, E);
    k_scan<<<1, 1024, 0, stream>>>(deg, rp, cursor, N);
    k_fill<<<(E + 255) / 256, 256, 0, stream>>>(srcI, dstI, cursor, colA, E);

    const int ablocks = (N + 3) / 4;
    const dim3 ggrid((N + 63) / 64, 2);

    // layer 1: h = relu(mean(x) @ W1_l + b1 + x @ W1_r)   [N,128]
    k_agg<<<ablocks, 256, 0, stream>>>(x, rp, colA, meanb, N);
    k_gemm<1><<<ggrid, 256, 0, stream>>>(
        meanb, x, W1_l, W1_l + 64, W1_r, W1_r + 64, b1, b1 + 64,
        h, h + 64, 128, 128, N);

    // layer 2: mu / logstd share mean(h); virtual col-split via blockIdx.y
    k_agg<<<ablocks, 256, 0, stream>>>(h, rp, colA, meanb, N);
    k_gemm<0><<<ggrid, 256, 0, stream>>>(
        meanb, h, Wmu_l, Wls_l, Wmu_r, Wls_r, bmu, bls,
        out_mu, out_ls, 64, 64, N);
}

// Round 4
// 3493.696 us; speedup vs baseline: 1.2724x; 1.2724x over previous
//
#include <hip/hip_runtime.h>

#define NODES_CH 128   // IN_CH == HID == 128
#define OUTW 64

// ---------------- CSR build ----------------

__global__ void k_zero(int* __restrict__ p, int n) {
    int i = blockIdx.x * blockDim.x + threadIdx.x;
    if (i < n) p[i] = 0;
}

__global__ void k_degree(const int* __restrict__ dstI, int* __restrict__ deg, int E) {
    int e = blockIdx.x * blockDim.x + threadIdx.x;
    if (e < E) atomicAdd(&deg[dstI[e]], 1);
}

// single-block exclusive scan; also inits cursor
__global__ __launch_bounds__(1024)
void k_scan(const int* __restrict__ deg, int* __restrict__ rp,
            int* __restrict__ cursor, int n) {
    __shared__ int wsum[16];
    int tid  = threadIdx.x;
    int lane = tid & 63;
    int wid  = tid >> 6;
    int carry = 0;
    for (int base = 0; base < n; base += 1024) {
        int i = base + tid;
        int v = (i < n) ? deg[i] : 0;
        int x = v;
        #pragma unroll
        for (int off = 1; off < 64; off <<= 1) {
            int t = __shfl_up(x, off, 64);
            if (lane >= off) x += t;
        }
        if (lane == 63) wsum[wid] = x;
        __syncthreads();
        if (wid == 0) {
            int y = (lane < 16) ? wsum[lane] : 0;
            #pragma unroll
            for (int off = 1; off < 16; off <<= 1) {
                int t = __shfl_up(y, off, 64);
                if (lane >= off) y += t;
            }
            if (lane < 16) wsum[lane] = y;
        }
        __syncthreads();
        int woff  = (wid > 0) ? wsum[wid - 1] : 0;
        int incl  = x + woff;
        int total = wsum[15];
        if (i < n) {
            int ex = carry + incl - v;
            rp[i] = ex;
            cursor[i] = ex;
        }
        carry += total;
        __syncthreads();  // protect wsum before next chunk overwrites
    }
    if (tid == 0) rp[n] = carry;
}

__global__ void k_fill(const int* __restrict__ srcI, const int* __restrict__ dstI,
                       int* __restrict__ cursor, int* __restrict__ colA, int E) {
    int e = blockIdx.x * blockDim.x + threadIdx.x;
    if (e < E) {
        int d = dstI[e];
        int p = atomicAdd(&cursor[d], 1);
        colA[p] = srcI[e];
    }
}

// ---------------- mean aggregation (gather over CSR) ----------------
// one WAVE per node; 32 lanes x float4 = one 512B row; lane halves take
// alternate edges (2 rows in flight per load instr), x2 manual unroll.
__global__ __launch_bounds__(256)
void k_agg(const float* __restrict__ X, const int* __restrict__ rp,
           const int* __restrict__ colA, float* __restrict__ out, int n) {
    int node = (blockIdx.x << 2) + (threadIdx.x >> 6);
    if (node >= n) return;
    int lane = threadIdx.x & 63;
    int eh = lane >> 5;   // which edge parity this half-wave takes
    int c4 = lane & 31;   // float4 slot within the 128-float row
    int beg = rp[node], end = rp[node + 1];
    const float4* __restrict__ X4 = (const float4*)X;
    float4 s = make_float4(0.f, 0.f, 0.f, 0.f);
    int e = beg + eh;
    // 2 edges per half-wave in flight
    for (; e + 2 < end; e += 4) {
        int c0 = colA[e];
        int c1 = colA[e + 2];
        float4 v0 = X4[(size_t)c0 * 32 + c4];
        float4 v1 = X4[(size_t)c1 * 32 + c4];
        s.x += v0.x + v1.x; s.y += v0.y + v1.y;
        s.z += v0.z + v1.z; s.w += v0.w + v1.w;
    }
    if (e < end) {
        int c0 = colA[e];
        float4 v0 = X4[(size_t)c0 * 32 + c4];
        s.x += v0.x; s.y += v0.y; s.z += v0.z; s.w += v0.w;
    }
    s.x += __shfl_xor(s.x, 32);
    s.y += __shfl_xor(s.y, 32);
    s.z += __shfl_xor(s.z, 32);
    s.w += __shfl_xor(s.w, 32);
    if (eh == 0) {
        float inv = 1.f / (float)((end > beg) ? (end - beg) : 1);
        ((float4*)out)[(size_t)node * 32 + c4] =
            make_float4(s.x * inv, s.y * inv, s.z * inv, s.w * inv);
    }
}

// ---------------- fused SAGE linear ----------------
// out(cols of this y-block) = A0 @ W0 + A1 @ W1 + bias, optional relu.
// Grid: (ceil(N/64), 2). Block 256 thr: cg=tid&15 (16 col groups x 4 cols),
// rg=tid>>4 (16 row groups x 4 rows) -> 64x64 tile, 4x4 acc/thread.
// cg in LOW lane bits: A-row address shared by 16 consecutive lanes
// (4 unique rows per wave-load), W LDS read = 16 consecutive float4
// (2-way bank alias = free).
// __launch_bounds__(256, 2): 2nd arg is min waves/EU — (256,4) clamps to
// 64 VGPR and SPILLS ACCUMULATORS TO SCRATCH (R2: 7.4 GB HBM traffic, 20x slow).
template <int RELU>
__global__ __launch_bounds__(256, 2)
void k_gemm(const float* __restrict__ A0, const float* __restrict__ A1,
            const float* __restrict__ W0a, const float* __restrict__ W0b,
            const float* __restrict__ W1a, const float* __restrict__ W1b,
            const float* __restrict__ ba, const float* __restrict__ bb,
            float* __restrict__ o0, float* __restrict__ o1,
            int wstride, int ostride, int N) {
    __shared__ float Wlds[64 * 64];  // 16 KiB
    const int tid = threadIdx.x;
    const int cg = tid & 15;
    const int rg = tid >> 4;
    const int cb = blockIdx.y;
    const int rbase = blockIdx.x * 64 + rg * 4;

    float acc[4][4];
    #pragma unroll
    for (int r = 0; r < 4; r++)
        #pragma unroll
        for (int c = 0; c < 4; c++) acc[r][c] = 0.f;

    #pragma unroll
    for (int phase = 0; phase < 2; ++phase) {
        const float* __restrict__ A = phase ? A1 : A0;
        const float* __restrict__ W = phase ? (cb ? W1b : W1a) : (cb ? W0b : W0a);
        for (int kc = 0; kc < 2; ++kc) {
            __syncthreads();
            // stage W rows [kc*64, kc*64+64), 64 cols -> Wlds[64][64]
            for (int i = tid; i < 64 * 16; i += 256) {
                int kr = i >> 4, c4 = i & 15;
                ((float4*)Wlds)[i] =
                    *(const float4*)(W + (size_t)(kc * 64 + kr) * wstride + c4 * 4);
            }
            __syncthreads();
            for (int k = 0; k < 64; k += 4) {
                float4 a[4];
                #pragma unroll
                for (int r = 0; r < 4; r++) {
                    int row = rbase + r;
                    a[r] = (row < N)
                        ? *(const float4*)(A + (size_t)row * 128 + kc * 64 + k)
                        : make_float4(0.f, 0.f, 0.f, 0.f);
                }
                #pragma unroll
                for (int kk = 0; kk < 4; kk++) {
                    float4 w = *(const float4*)(Wlds + (k + kk) * 64 + cg * 4);
                    #pragma unroll
                    for (int r = 0; r < 4; r++) {
                        float av = (kk == 0) ? a[r].x : (kk == 1) ? a[r].y
                                 : (kk == 2) ? a[r].z : a[r].w;
                        acc[r][0] += av * w.x;
                        acc[r][1] += av * w.y;
                        acc[r][2] += av * w.z;
                        acc[r][3] += av * w.w;
                    }
                }
            }
        }
    }

    const float4 bv = *(const float4*)((cb ? bb : ba) + cg * 4);
    float* __restrict__ obase = cb ? o1 : o0;
    #pragma unroll
    for (int r = 0; r < 4; r++) {
        int row = rbase + r;
        if (row >= N) continue;
        float4 v;
        v.x = acc[r][0] + bv.x;
        v.y = acc[r][1] + bv.y;
        v.z = acc[r][2] + bv.z;
        v.w = acc[r][3] + bv.w;
        if (RELU) {
            v.x = fmaxf(v.x, 0.f); v.y = fmaxf(v.y, 0.f);
            v.z = fmaxf(v.z, 0.f); v.w = fmaxf(v.w, 0.f);
        }
        *(float4*)(obase + (size_t)row * ostride + cg * 4) = v;
    }
}

// ---------------- launch ----------------

extern "C" void kernel_launch(void* const* d_in, const int* in_sizes, int n_in,
                              void* d_out, int out_size, void* d_ws, size_t ws_size,
                              hipStream_t stream) {
    const float* x     = (const float*)d_in[0];
    const int*   ei    = (const int*)d_in[1];
    const float* W1_l  = (const float*)d_in[2];
    const float* b1    = (const float*)d_in[3];
    const float* W1_r  = (const float*)d_in[4];
    const float* Wmu_l = (const float*)d_in[5];
    const float* bmu   = (const float*)d_in[6];
    const float* Wmu_r = (const float*)d_in[7];
    const float* Wls_l = (const float*)d_in[8];
    const float* bls   = (const float*)d_in[9];
    const float* Wls_r = (const float*)d_in[10];

    const int N = in_sizes[0] / NODES_CH;  // 50000
    const int E = in_sizes[1] / 2;         // 800000
    const int* srcI = ei;
    const int* dstI = ei + E;

    const int NP = (N + 63) & ~63;
    const int EP = (E + 15) & ~15;

    char* w = (char*)d_ws;
    int* deg    = (int*)w;  w += (size_t)NP * 4;
    int* rp     = (int*)w;  w += (size_t)(NP + 64) * 4;
    int* cursor = (int*)w;  w += (size_t)NP * 4;
    int* colA   = (int*)w;  w += (size_t)EP * 4;
    float* meanb = (float*)w;  w += (size_t)N * 128 * 4;
    float* h     = (float*)w;  w += (size_t)N * 128 * 4;

    float* out_mu = (float*)d_out;
    float* out_ls = out_mu + (size_t)N * OUTW;

    // CSR build
    k_zero<<<(N + 255) / 256, 256, 0, stream>>>(deg, N);
    k_degree<<<(E + 255) / 256, 256, 0, stream>>>(dstI, deg, E);
    k_scan<<<1, 1024, 0, stream>>>(deg, rp, cursor, N);
    k_fill<<<(E + 255) / 256, 256, 0, stream>>>(srcI, dstI, cursor, colA, E);

    const int ablocks = (N + 3) / 4;
    const dim3 ggrid((N + 63) / 64, 2);

    // layer 1: h = relu(mean(x) @ W1_l + b1 + x @ W1_r)   [N,128]
    k_agg<<<ablocks, 256, 0, stream>>>(x, rp, colA, meanb, N);
    k_gemm<1><<<ggrid, 256, 0, stream>>>(
        meanb, x, W1_l, W1_l + 64, W1_r, W1_r + 64, b1, b1 + 64,
        h, h + 64, 128, 128, N);

    // layer 2: mu / logstd share mean(h); virtual col-split via blockIdx.y
    k_agg<<<ablocks, 256, 0, stream>>>(h, rp, colA, meanb, N);
    k_gemm<0><<<ggrid, 256, 0, stream>>>(
        meanb, h, Wmu_l, Wls_l, Wmu_r, Wls_r, bmu, bls,
        out_mu, out_ls, 64, 64, N);
}

// Round 5
// 539.673 us; speedup vs baseline: 8.2373x; 6.4737x over previous
//
#include <hip/hip_runtime.h>

#define NODES_CH 128   // IN_CH == HID == 128
#define OUTW 64

// ---------------- CSR build ----------------

__global__ void k_zero(int* __restrict__ p, int n) {
    int i = blockIdx.x * blockDim.x + threadIdx.x;
    if (i < n) p[i] = 0;
}

__global__ void k_degree(const int* __restrict__ dstI, int* __restrict__ deg, int E) {
    int e = blockIdx.x * blockDim.x + threadIdx.x;
    if (e < E) atomicAdd(&deg[dstI[e]], 1);
}

// single-block exclusive scan; also inits cursor
__global__ __launch_bounds__(1024)
void k_scan(const int* __restrict__ deg, int* __restrict__ rp,
            int* __restrict__ cursor, int n) {
    __shared__ int wsum[16];
    int tid  = threadIdx.x;
    int lane = tid & 63;
    int wid  = tid >> 6;
    int carry = 0;
    for (int base = 0; base < n; base += 1024) {
        int i = base + tid;
        int v = (i < n) ? deg[i] : 0;
        int x = v;
        #pragma unroll
        for (int off = 1; off < 64; off <<= 1) {
            int t = __shfl_up(x, off, 64);
            if (lane >= off) x += t;
        }
        if (lane == 63) wsum[wid] = x;
        __syncthreads();
        if (wid == 0) {
            int y = (lane < 16) ? wsum[lane] : 0;
            #pragma unroll
            for (int off = 1; off < 16; off <<= 1) {
                int t = __shfl_up(y, off, 64);
                if (lane >= off) y += t;
            }
            if (lane < 16) wsum[lane] = y;
        }
        __syncthreads();
        int woff  = (wid > 0) ? wsum[wid - 1] : 0;
        int incl  = x + woff;
        int total = wsum[15];
        if (i < n) {
            int ex = carry + incl - v;
            rp[i] = ex;
            cursor[i] = ex;
        }
        carry += total;
        __syncthreads();  // protect wsum before next chunk overwrites
    }
    if (tid == 0) rp[n] = carry;
}

__global__ void k_fill(const int* __restrict__ srcI, const int* __restrict__ dstI,
                       int* __restrict__ cursor, int* __restrict__ colA, int E) {
    int e = blockIdx.x * blockDim.x + threadIdx.x;
    if (e < E) {
        int d = dstI[e];
        int p = atomicAdd(&cursor[d], 1);
        colA[p] = srcI[e];
    }
}

// ---------------- mean aggregation (gather over CSR) ----------------
// one WAVE per node; 32 lanes x float4 = one 512B row; lane halves take
// alternate edges (2 rows in flight per load instr).
__global__ __launch_bounds__(256)
void k_agg(const float* __restrict__ X, const int* __restrict__ rp,
           const int* __restrict__ colA, float* __restrict__ out, int n) {
    int node = (blockIdx.x << 2) + (threadIdx.x >> 6);
    if (node >= n) return;
    int lane = threadIdx.x & 63;
    int eh = lane >> 5;   // which edge parity this half-wave takes
    int c4 = lane & 31;   // float4 slot within the 128-float row
    int beg = rp[node], end = rp[node + 1];
    const float4* __restrict__ X4 = (const float4*)X;
    float4 s = make_float4(0.f, 0.f, 0.f, 0.f);
    int e = beg + eh;
    for (; e + 2 < end; e += 4) {
        int c0 = colA[e];
        int c1 = colA[e + 2];
        float4 v0 = X4[(size_t)c0 * 32 + c4];
        float4 v1 = X4[(size_t)c1 * 32 + c4];
        s.x += v0.x + v1.x; s.y += v0.y + v1.y;
        s.z += v0.z + v1.z; s.w += v0.w + v1.w;
    }
    if (e < end) {
        int c0 = colA[e];
        float4 v0 = X4[(size_t)c0 * 32 + c4];
        s.x += v0.x; s.y += v0.y; s.z += v0.z; s.w += v0.w;
    }
    s.x += __shfl_xor(s.x, 32);
    s.y += __shfl_xor(s.y, 32);
    s.z += __shfl_xor(s.z, 32);
    s.w += __shfl_xor(s.w, 32);
    if (eh == 0) {
        float inv = 1.f / (float)((end > beg) ? (end - beg) : 1);
        ((float4*)out)[(size_t)node * 32 + c4] =
            make_float4(s.x * inv, s.y * inv, s.z * inv, s.w * inv);
    }
}

// ---------------- fused SAGE linear ----------------
// R0-proven structure (R1 bench: 92 VGPR, no scratch traffic), halved rows.
// out = A0 @ W(phase0) + A1 @ W(phase1) + bias; MODE 0 adds relu (128 cols,
// stride 128); MODE 1 packs [Wmu | Wls] as virtual 128 cols, split outputs
// (stride 64 each). 1D grid: ceil(N/64) blocks of 256 thr.
// Thread map: cg=tid&15 -> cols {cg*4..+3} and {64+cg*4..+3}; rg=tid>>4 ->
// 4 rows. W LDS reads at 16B stride = 2-way bank alias (free); R0's 32B
// stride was a 4-way conflict (3.2M SQ_LDS_BANK_CONFLICT).
// k-loop pragma'd "unroll 2" ONLY — R2/R4's scratch blowup (5.4 GB HBM
// traffic, VALUBusy 1.8%) correlated with compiler over-unroll/pipelining
// of the small un-annotated inner body; keep in-flight loads ~8 float4.
template <int MODE>
__global__ __launch_bounds__(256, 2)
void k_gemm(const float* __restrict__ A0, const float* __restrict__ A1,
            const float* __restrict__ Wa0, const float* __restrict__ Wb0,
            const float* __restrict__ Wa1, const float* __restrict__ Wb1,
            const float* __restrict__ ba, const float* __restrict__ bb,
            float* __restrict__ out0, float* __restrict__ out1, int N) {
    __shared__ float Wlds[64 * 128];  // 32 KiB: one 64-k chunk x 128 cols
    const int tid = threadIdx.x;
    const int cg  = tid & 15;
    const int rg  = tid >> 4;
    const int rbase = blockIdx.x * 64 + rg * 4;

    float acc[4][8];
    #pragma unroll
    for (int r = 0; r < 4; r++)
        #pragma unroll
        for (int c = 0; c < 8; c++) acc[r][c] = 0.f;

    for (int phase = 0; phase < 2; ++phase) {
        const float* __restrict__ A = phase ? A1 : A0;
        for (int kc = 0; kc < 2; ++kc) {
            __syncthreads();
            if (MODE == 0) {
                const float* __restrict__ W = phase ? Wa1 : Wa0;  // [128][128]
                for (int i = tid; i < 2048; i += 256) {
                    int kr = i >> 5, c4 = i & 31;
                    ((float4*)Wlds)[i] =
                        *(const float4*)(W + (size_t)(kc * 64 + kr) * 128 + c4 * 4);
                }
            } else {
                const float* __restrict__ WA = phase ? Wa1 : Wa0;  // [128][64] mu
                const float* __restrict__ WB = phase ? Wb1 : Wb0;  // [128][64] ls
                for (int i = tid; i < 2048; i += 256) {
                    int kr = i >> 5, c4 = i & 31;
                    const float* s = (c4 < 16)
                        ? (WA + (size_t)(kc * 64 + kr) * 64 + c4 * 4)
                        : (WB + (size_t)(kc * 64 + kr) * 64 + (c4 - 16) * 4);
                    ((float4*)Wlds)[i] = *(const float4*)s;
                }
            }
            __syncthreads();
            #pragma unroll 2
            for (int k = 0; k < 64; k += 4) {
                float4 a[4];
                #pragma unroll
                for (int r = 0; r < 4; r++) {
                    int row = rbase + r;
                    a[r] = (row < N)
                        ? *(const float4*)(A + (size_t)row * 128 + kc * 64 + k)
                        : make_float4(0.f, 0.f, 0.f, 0.f);
                }
                #pragma unroll
                for (int kk = 0; kk < 4; kk++) {
                    float4 w0 = *(const float4*)(Wlds + (k + kk) * 128 + cg * 4);
                    float4 w1 = *(const float4*)(Wlds + (k + kk) * 128 + 64 + cg * 4);
                    #pragma unroll
                    for (int r = 0; r < 4; r++) {
                        float av = (kk == 0) ? a[r].x : (kk == 1) ? a[r].y
                                 : (kk == 2) ? a[r].z : a[r].w;
                        acc[r][0] += av * w0.x;
                        acc[r][1] += av * w0.y;
                        acc[r][2] += av * w0.z;
                        acc[r][3] += av * w0.w;
                        acc[r][4] += av * w1.x;
                        acc[r][5] += av * w1.y;
                        acc[r][6] += av * w1.z;
                        acc[r][7] += av * w1.w;
                    }
                }
            }
        }
    }

    // epilogue
    if (MODE == 0) {
        const float4 bv0 = *(const float4*)(ba + cg * 4);
        const float4 bv1 = *(const float4*)(ba + 64 + cg * 4);
        #pragma unroll
        for (int r = 0; r < 4; r++) {
            int row = rbase + r;
            if (row >= N) continue;
            float4 v0, v1;
            v0.x = fmaxf(acc[r][0] + bv0.x, 0.f);
            v0.y = fmaxf(acc[r][1] + bv0.y, 0.f);
            v0.z = fmaxf(acc[r][2] + bv0.z, 0.f);
            v0.w = fmaxf(acc[r][3] + bv0.w, 0.f);
            v1.x = fmaxf(acc[r][4] + bv1.x, 0.f);
            v1.y = fmaxf(acc[r][5] + bv1.y, 0.f);
            v1.z = fmaxf(acc[r][6] + bv1.z, 0.f);
            v1.w = fmaxf(acc[r][7] + bv1.w, 0.f);
            *(float4*)(out0 + (size_t)row * 128 + cg * 4) = v0;
            *(float4*)(out0 + (size_t)row * 128 + 64 + cg * 4) = v1;
        }
    } else {
        const float4 bm = *(const float4*)(ba + cg * 4);
        const float4 bl = *(const float4*)(bb + cg * 4);
        #pragma unroll
        for (int r = 0; r < 4; r++) {
            int row = rbase + r;
            if (row >= N) continue;
            float4 vm, vl;
            vm.x = acc[r][0] + bm.x; vm.y = acc[r][1] + bm.y;
            vm.z = acc[r][2] + bm.z; vm.w = acc[r][3] + bm.w;
            vl.x = acc[r][4] + bl.x; vl.y = acc[r][5] + bl.y;
            vl.z = acc[r][6] + bl.z; vl.w = acc[r][7] + bl.w;
            *(float4*)(out0 + (size_t)row * 64 + cg * 4) = vm;
            *(float4*)(out1 + (size_t)row * 64 + cg * 4) = vl;
        }
    }
}

// ---------------- launch ----------------

extern "C" void kernel_launch(void* const* d_in, const int* in_sizes, int n_in,
                              void* d_out, int out_size, void* d_ws, size_t ws_size,
                              hipStream_t stream) {
    const float* x     = (const float*)d_in[0];
    const int*   ei    = (const int*)d_in[1];
    const float* W1_l  = (const float*)d_in[2];
    const float* b1    = (const float*)d_in[3];
    const float* W1_r  = (const float*)d_in[4];
    const float* Wmu_l = (const float*)d_in[5];
    const float* bmu   = (const float*)d_in[6];
    const float* Wmu_r = (const float*)d_in[7];
    const float* Wls_l = (const float*)d_in[8];
    const float* bls   = (const float*)d_in[9];
    const float* Wls_r = (const float*)d_in[10];

    const int N = in_sizes[0] / NODES_CH;  // 50000
    const int E = in_sizes[1] / 2;         // 800000
    const int* srcI = ei;
    const int* dstI = ei + E;

    const int NP = (N + 63) & ~63;
    const int EP = (E + 15) & ~15;

    char* w = (char*)d_ws;
    int* deg    = (int*)w;  w += (size_t)NP * 4;
    int* rp     = (int*)w;  w += (size_t)(NP + 64) * 4;
    int* cursor = (int*)w;  w += (size_t)NP * 4;
    int* colA   = (int*)w;  w += (size_t)EP * 4;
    float* meanb = (float*)w;  w += (size_t)N * 128 * 4;
    float* h     = (float*)w;  w += (size_t)N * 128 * 4;

    float* out_mu = (float*)d_out;
    float* out_ls = out_mu + (size_t)N * OUTW;

    // CSR build
    k_zero<<<(N + 255) / 256, 256, 0, stream>>>(deg, N);
    k_degree<<<(E + 255) / 256, 256, 0, stream>>>(dstI, deg, E);
    k_scan<<<1, 1024, 0, stream>>>(deg, rp, cursor, N);
    k_fill<<<(E + 255) / 256, 256, 0, stream>>>(srcI, dstI, cursor, colA, E);

    const int ablocks = (N + 3) / 4;
    const int gblocks = (N + 63) / 64;

    // layer 1: h = relu(mean(x) @ W1_l + b1 + x @ W1_r)   [N,128]
    k_agg<<<ablocks, 256, 0, stream>>>(x, rp, colA, meanb, N);
    k_gemm<0><<<gblocks, 256, 0, stream>>>(
        meanb, x, W1_l, nullptr, W1_r, nullptr, b1, nullptr, h, nullptr, N);

    // layer 2: mu / logstd share mean(h)
    k_agg<<<ablocks, 256, 0, stream>>>(h, rp, colA, meanb, N);
    k_gemm<1><<<gblocks, 256, 0, stream>>>(
        meanb, h, Wmu_l, Wls_l, Wmu_r, Wls_r, bmu, bls, out_mu, out_ls, N);
}